// Round 9
// baseline (47.686 us; speedup 1.0000x reference)
//
#include <hip/hip_runtime.h>
#include <hip/hip_bf16.h>

#define BATCH 4096
#define DIM   512
#define NLBL  512
#define BIGF  1e4f
#define MARGIN 1.0f

#define BM 64         // per-wave tile
#define BK 32         // bf16 elems per K-step
#define NT (BATCH/BM) // 64
#define NPAIR (NT*(NT+1)/2)  // 2080
#define NBLK (NPAIR/2)       // 1040 blocks x 2 waves
#define KITERS (DIM/BK)      // 16

using f32x4  = __attribute__((ext_vector_type(4))) float;
using bf16x8 = __attribute__((ext_vector_type(8))) short;

__device__ __forceinline__ unsigned short f2bf(float x) {
    __hip_bfloat16 h = __float2bfloat16(x);
    return *reinterpret_cast<unsigned short*>(&h);
}

#define GLOAD16(gp, lp) \
    __builtin_amdgcn_global_load_lds((const __attribute__((address_space(1))) void*)(gp), \
                                     (__attribute__((address_space(3))) void*)(lp), 16, 0, 0)

// ---------------- kernel 1: row L2-normalize -> bf16 (+ hp/hn init fused) ----------------
__global__ __launch_bounds__(256) void normalize_k(const float* __restrict__ emb,
                                                   unsigned short* __restrict__ Hi,
                                                   unsigned* __restrict__ hp,
                                                   unsigned* __restrict__ hn) {
    int wave = threadIdx.x >> 6;
    int lane = threadIdx.x & 63;
    int row  = blockIdx.x * 4 + wave;
    const float4* src = (const float4*)(emb + (size_t)row * DIM);
    float4 v0 = src[lane * 2];
    float4 v1 = src[lane * 2 + 1];
    float ss = v0.x*v0.x + v0.y*v0.y + v0.z*v0.z + v0.w*v0.w
             + v1.x*v1.x + v1.y*v1.y + v1.z*v1.z + v1.w*v1.w;
    #pragma unroll
    for (int off = 1; off < 64; off <<= 1) ss += __shfl_xor(ss, off);
    float scale = 1.0f / fmaxf(sqrtf(ss), 1e-12f);
    bf16x8 o;
    o[0] = (short)f2bf(v0.x * scale);
    o[1] = (short)f2bf(v0.y * scale);
    o[2] = (short)f2bf(v0.z * scale);
    o[3] = (short)f2bf(v0.w * scale);
    o[4] = (short)f2bf(v1.x * scale);
    o[5] = (short)f2bf(v1.y * scale);
    o[6] = (short)f2bf(v1.z * scale);
    o[7] = (short)f2bf(v1.w * scale);
    *(bf16x8*)(Hi + (size_t)row * DIM + lane * 8) = o;
    if (lane == 0) {
        hp[row] = 0u;
        hn[row] = __float_as_uint(BIGF);
    }
}

// ---------------- kernel 2: fused bf16 MFMA sim + batch-hard mining ----------------
// Fully decoupled: each WAVE owns one upper-triangle 64x64 tile-pair and a
// private 16KB LDS slice (A/B double-buffered, BK=32). ZERO barriers.
// Per-wave counted-vmcnt pipeline: 16 loads (2 tiles) in flight; WAR on the
// LDS buffer protected by lgkmcnt(0) before restage. Latency hidden by ~10
// independent waves/CU, all 1040 blocks resident.
__global__ __launch_bounds__(128, 4) void mine_k(const unsigned short* __restrict__ Hi,
                                                 const int* __restrict__ lab,
                                                 unsigned* __restrict__ hp,
                                                 unsigned* __restrict__ hn) {
    __shared__ __attribute__((aligned(16))) unsigned short As[2][2][BM * BK]; // 16 KB
    __shared__ __attribute__((aligned(16))) unsigned short Bs[2][2][BM * BK]; // 16 KB

    const int tid  = threadIdx.x;
    const int w    = tid >> 6;      // wave 0..1
    const int lane = tid & 63;
    const int l15  = lane & 15;
    const int lhi  = lane >> 4;     // 0..3

    // XCD-aware swizzle (1040 = 8*130, bijective), then per-wave pair index
    int bb = (int)blockIdx.x;
    bb = (bb & 7) * (NBLK / 8) + (bb >> 3);
    int p = bb * 2 + w;
    int bi = 0, rem = p;
    while (rem >= NT - bi) { rem -= NT - bi; ++bi; }
    int bj = bi + rem;
    const int i0 = bi * BM;
    const int j0 = bj * BM;

    f32x4 acc[4][4] = {};
    const char* HiB = (const char*)Hi;
    unsigned short (*A)[BM * BK] = As[w];
    unsigned short (*B)[BM * BK] = Bs[w];

    // stage one 64x32 K-chunk of A and B: 4 GLOAD16 each (16 rows x 64B per instr)
    // lane l -> row q*16+(l>>2); phys chunk l&3 holds logical (l&3)^((row>>1)&3)
    auto STAGE = [&](int buf, int t) {
        const size_t kb = (size_t)t * (BK * 2);
        #pragma unroll
        for (int q = 0; q < 4; ++q) {
            int lr = q * 16 + (lane >> 2);
            int sc = (lane & 3) ^ ((lr >> 1) & 3);
            const char* ga = HiB + (size_t)(i0 + lr) * (DIM * 2) + kb + (sc << 4);
            const char* gb = HiB + (size_t)(j0 + lr) * (DIM * 2) + kb + (sc << 4);
            GLOAD16(ga, (char*)A[buf] + q * 1024);
            GLOAD16(gb, (char*)B[buf] + q * 1024);
        }
    };

    // ---- barrier-free counted-vmcnt K-loop ----
    STAGE(0, 0);
    STAGE(1, 1);          // 16 loads in flight
    #pragma unroll
    for (int t = 0; t < KITERS; ++t) {
        const int cur = t & 1;
        if (t < KITERS - 1) {
            asm volatile("s_waitcnt vmcnt(8)" ::: "memory");   // tile t landed; t+1 in flight
        } else {
            asm volatile("s_waitcnt vmcnt(0)" ::: "memory");
        }
        __builtin_amdgcn_sched_barrier(0);

        bf16x8 a[4], b[4];
        #pragma unroll
        for (int m = 0; m < 4; ++m) {
            int row = m * 16 + l15;
            int cp  = lhi ^ ((row >> 1) & 3);
            a[m] = *(const bf16x8*)((const char*)A[cur] + row * 64 + (cp << 4));
        }
        #pragma unroll
        for (int n = 0; n < 4; ++n) {
            int row = n * 16 + l15;
            int cp  = lhi ^ ((row >> 1) & 3);
            b[n] = *(const bf16x8*)((const char*)B[cur] + row * 64 + (cp << 4));
        }
        // fragment reads complete -> safe to overwrite this buffer (WAR)
        asm volatile("s_waitcnt lgkmcnt(0)" ::: "memory");
        __builtin_amdgcn_sched_barrier(0);
        if (t + 2 < KITERS) STAGE(cur, t + 2);

        #pragma unroll
        for (int m = 0; m < 4; ++m)
            #pragma unroll
            for (int n = 0; n < 4; ++n)
                acc[m][n] = __builtin_amdgcn_mfma_f32_16x16x32_bf16(a[m], b[n], acc[m][n], 0, 0, 0);
    }

    // ---- labels (after K-loop so they don't pollute vmcnt counts) ----
    int lj[4];
    #pragma unroll
    for (int n = 0; n < 4; ++n) lj[n] = lab[j0 + n * 16 + l15];
    int li[16];
    #pragma unroll
    for (int m = 0; m < 4; ++m)
        #pragma unroll
        for (int r = 0; r < 4; ++r)
            li[m * 4 + r] = lab[i0 + m * 16 + lhi * 4 + r];

    // ---- epilogue (per-wave, in-register, direct atomics) ----
    // C[i][j]: i = i0 + m*16 + lhi*4 + r ; j = j0 + n*16 + l15
    #pragma unroll
    for (int m = 0; m < 4; ++m) {
        #pragma unroll
        for (int r = 0; r < 4; ++r) {
            int i   = i0 + m * 16 + lhi * 4 + r;
            int lir = li[m * 4 + r];
            float pm = 0.0f, nm = BIGF;
            #pragma unroll
            for (int n = 0; n < 4; ++n) {
                float dist = fmaxf(1.0f - acc[m][n][r], 0.0f);
                int j = j0 + n * 16 + l15;
                if (lir == lj[n]) {
                    if (i != j) pm = fmaxf(pm, dist);
                } else {
                    nm = fminf(nm, dist);
                }
            }
            #pragma unroll
            for (int off = 1; off < 16; off <<= 1) {
                pm = fmaxf(pm, __shfl_xor(pm, off));
                nm = fminf(nm, __shfl_xor(nm, off));
            }
            if (l15 == 0) {
                atomicMax(hp + i, __float_as_uint(pm));
                atomicMin(hn + i, __float_as_uint(nm));
            }
        }
    }

    #pragma unroll
    for (int n = 0; n < 4; ++n) {
        int j   = j0 + n * 16 + l15;
        int ljn = lj[n];
        float cp = 0.0f, cn = BIGF;
        #pragma unroll
        for (int m = 0; m < 4; ++m) {
            #pragma unroll
            for (int r = 0; r < 4; ++r) {
                float dist = fmaxf(1.0f - acc[m][n][r], 0.0f);
                int i = i0 + m * 16 + lhi * 4 + r;
                if (li[m * 4 + r] == ljn) {
                    if (i != j) cp = fmaxf(cp, dist);
                } else {
                    cn = fminf(cn, dist);
                }
            }
        }
        #pragma unroll
        for (int off = 16; off < 64; off <<= 1) {
            cp = fmaxf(cp, __shfl_xor(cp, off));
            cn = fminf(cn, __shfl_xor(cn, off));
        }
        if (lhi == 0) {
            atomicMax(hp + j, __float_as_uint(cp));
            atomicMin(hn + j, __float_as_uint(cn));
        }
    }
}

// ---------------- kernel 3: finalize ----------------
__global__ __launch_bounds__(1024) void final_k(const int* __restrict__ lab,
                                                const unsigned* __restrict__ hp,
                                                const unsigned* __restrict__ hn,
                                                float* __restrict__ out) {
    __shared__ int   cnt[NLBL];
    __shared__ float ssum[16];
    __shared__ int   scnt[16];
    int t = threadIdx.x;
    for (int i = t; i < NLBL; i += 1024) cnt[i] = 0;
    __syncthreads();
    for (int i = t; i < BATCH; i += 1024) atomicAdd(&cnt[lab[i]], 1);
    __syncthreads();

    float lsum = 0.0f;
    int   lcnt = 0;
    for (int i = t; i < BATCH; i += 1024) {
        int c = cnt[lab[i]];
        if ((c > 1) && (c < BATCH)) {
            float per = fmaxf(__uint_as_float(hp[i]) - __uint_as_float(hn[i]) + MARGIN, 0.0f);
            lsum += per;
            lcnt += 1;
        }
    }
    #pragma unroll
    for (int off = 1; off < 64; off <<= 1) {
        lsum += __shfl_xor(lsum, off);
        lcnt += __shfl_xor(lcnt, off);
    }
    int w = t >> 6;
    if ((t & 63) == 0) { ssum[w] = lsum; scnt[w] = lcnt; }
    __syncthreads();
    if (t == 0) {
        float s = 0.0f; int c2 = 0;
        #pragma unroll
        for (int i = 0; i < 16; ++i) { s += ssum[i]; c2 += scnt[i]; }
        out[0] = s / (float)max(c2, 1);
    }
}

// ---------------- launcher ----------------
extern "C" void kernel_launch(void* const* d_in, const int* in_sizes, int n_in,
                              void* d_out, int out_size, void* d_ws, size_t ws_size,
                              hipStream_t stream) {
    const float* emb = (const float*)d_in[0];
    const int*   lab = (const int*)d_in[1];

    char* base = (char*)d_ws;
    unsigned short* Hi = (unsigned short*)base;                       // 4 MB
    unsigned* hp = (unsigned*)(base + (size_t)BATCH * DIM * 2);       // 16 KB
    unsigned* hn = hp + BATCH;                                        // 16 KB

    normalize_k<<<BATCH / 4, 256, 0, stream>>>(emb, Hi, hp, hn);
    mine_k<<<NBLK, 128, 0, stream>>>(Hi, lab, hp, hn);
    final_k<<<1, 1024, 0, stream>>>(lab, hp, hn, (float*)d_out);
}

// Round 10
// 37.203 us; speedup vs baseline: 1.2818x; 1.2818x over previous
//
#include <hip/hip_runtime.h>
#include <hip/hip_bf16.h>

#define BATCH 4096
#define DIM   512
#define NLBL  512
#define BIGF  1e4f
#define MARGIN 1.0f

#define BM 128        // tile (rows = cols)
#define BK 32         // bf16 elems per K-step (36KB LDS -> 4 blocks/CU, all resident)
#define NT (BATCH/BM) // 32
#define NPAIR (NT*(NT+1)/2)  // 528
#define KITERS (DIM/BK)      // 16

using f32x4  = __attribute__((ext_vector_type(4))) float;
using bf16x8 = __attribute__((ext_vector_type(8))) short;

// ---- compile-time pair table: supercell-compact enumeration of the triangle ----
// 4x4 supercells of the 32x32 tile triangle, BI-row-major; within-cell row-major.
// Consecutive 66-pair runs (one per XCD via %8 round-robin) then touch only
// ~4 i-panels + ~20 j-panels ~= 3MB < 4MB per-XCD L2.
struct PairTab { unsigned char bi[NPAIR]; unsigned char bj[NPAIR]; };
constexpr PairTab make_tab() {
    PairTab t{};
    int idx = 0;
    for (int BI = 0; BI < 8; ++BI)
        for (int BJ = BI; BJ < 8; ++BJ)
            for (int ii = 0; ii < 4; ++ii)
                for (int jj = 0; jj < 4; ++jj) {
                    int i = BI * 4 + ii, j = BJ * 4 + jj;
                    if (i <= j) {
                        t.bi[idx] = (unsigned char)i;
                        t.bj[idx] = (unsigned char)j;
                        ++idx;
                    }
                }
    return t;
}
__device__ constexpr PairTab PT = make_tab();

__device__ __forceinline__ unsigned short f2bf(float x) {
    __hip_bfloat16 h = __float2bfloat16(x);
    return *reinterpret_cast<unsigned short*>(&h);
}

#define GLOAD16(gp, lp) \
    __builtin_amdgcn_global_load_lds((const __attribute__((address_space(1))) void*)(gp), \
                                     (__attribute__((address_space(3))) void*)(lp), 16, 0, 0)

// ---------------- kernel 1: row L2-normalize -> bf16 (+ hp/hn init fused) ----------------
__global__ __launch_bounds__(256) void normalize_k(const float* __restrict__ emb,
                                                   unsigned short* __restrict__ Hi,
                                                   unsigned* __restrict__ hp,
                                                   unsigned* __restrict__ hn) {
    int wave = threadIdx.x >> 6;
    int lane = threadIdx.x & 63;
    int row  = blockIdx.x * 4 + wave;
    const float4* src = (const float4*)(emb + (size_t)row * DIM);
    float4 v0 = src[lane * 2];
    float4 v1 = src[lane * 2 + 1];
    float ss = v0.x*v0.x + v0.y*v0.y + v0.z*v0.z + v0.w*v0.w
             + v1.x*v1.x + v1.y*v1.y + v1.z*v1.z + v1.w*v1.w;
    #pragma unroll
    for (int off = 1; off < 64; off <<= 1) ss += __shfl_xor(ss, off);
    float scale = 1.0f / fmaxf(sqrtf(ss), 1e-12f);
    bf16x8 o;
    o[0] = (short)f2bf(v0.x * scale);
    o[1] = (short)f2bf(v0.y * scale);
    o[2] = (short)f2bf(v0.z * scale);
    o[3] = (short)f2bf(v0.w * scale);
    o[4] = (short)f2bf(v1.x * scale);
    o[5] = (short)f2bf(v1.y * scale);
    o[6] = (short)f2bf(v1.z * scale);
    o[7] = (short)f2bf(v1.w * scale);
    *(bf16x8*)(Hi + (size_t)row * DIM + lane * 8) = o;
    if (lane == 0) {
        hp[row] = 0u;
        hn[row] = __float_as_uint(BIGF);
    }
}

// ---------------- kernel 2: fused bf16 MFMA sim + batch-hard mining ----------------
// R7 structure (best): BK=32 double-buffered, counted-vmcnt, 2 barriers/step,
// 4 blocks/CU capacity -> all 528 blocks resident. Only change vs R7: the
// supercell-compact XCD-clustered pair mapping (L2 locality).
__global__ __launch_bounds__(256, 4) void mine_k(const unsigned short* __restrict__ Hi,
                                                 const int* __restrict__ lab,
                                                 unsigned* __restrict__ hp,
                                                 unsigned* __restrict__ hn) {
    __shared__ __attribute__((aligned(16))) unsigned short As[2][BM * BK]; // 16 KB
    __shared__ __attribute__((aligned(16))) unsigned short Bs[2][BM * BK]; // 16 KB
    __shared__ float rowp[2][BM], rown[2][BM], colp[2][BM], coln[2][BM];   // 4 KB

    // XCD-clustered mapping: XCD x = blockIdx%8 gets run [x*66, x*66+66) of the
    // supercell-compact pair table.
    int orig = (int)blockIdx.x;
    int p = (orig & 7) * (NPAIR / 8) + (orig >> 3);
    const int bi = PT.bi[p];
    const int bj = PT.bj[p];
    const int i0 = bi * BM;
    const int j0 = bj * BM;

    const int tid  = threadIdx.x;
    const int w    = tid >> 6;
    const int lane = tid & 63;
    const int wr   = w >> 1;
    const int wc   = w & 1;
    const int l15  = lane & 15;
    const int lhi  = lane >> 4;     // 0..3 : 16B k-chunk within 64B row

    f32x4 acc[4][4] = {};
    const char* HiB = (const char*)Hi;

    // stage: per wave 2 instrs/matrix; instr covers 16 rows x 64B.
    // lane l -> row +(l>>2), phys chunk l&3 holds logical (l&3)^((row>>1)&3).
    auto STAGE = [&](int buf, int t) {
        const size_t kb = (size_t)t * (BK * 2);
        #pragma unroll
        for (int q = 0; q < 2; ++q) {
            int r16 = w * 32 + q * 16;
            int lr  = r16 + (lane >> 2);
            int sc  = (lane & 3) ^ ((lr >> 1) & 3);
            const char* ga = HiB + (size_t)(i0 + lr) * (DIM * 2) + kb + (sc << 4);
            const char* gb = HiB + (size_t)(j0 + lr) * (DIM * 2) + kb + (sc << 4);
            GLOAD16(ga, (char*)As[buf] + r16 * 64);
            GLOAD16(gb, (char*)Bs[buf] + r16 * 64);
        }
    };
    // compute: one MFMA K-slice per step (BK=32). 2-way bank aliasing max (free).
    auto COMPUTE = [&](int buf) {
        bf16x8 a[4], b[4];
        #pragma unroll
        for (int m = 0; m < 4; ++m) {
            int row = wr * 64 + m * 16 + l15;
            int cp  = lhi ^ ((row >> 1) & 3);
            a[m] = *(const bf16x8*)((const char*)As[buf] + row * 64 + (cp << 4));
        }
        #pragma unroll
        for (int n = 0; n < 4; ++n) {
            int row = wc * 64 + n * 16 + l15;
            int cp  = lhi ^ ((row >> 1) & 3);
            b[n] = *(const bf16x8*)((const char*)Bs[buf] + row * 64 + (cp << 4));
        }
        #pragma unroll
        for (int m = 0; m < 4; ++m)
            #pragma unroll
            for (int n = 0; n < 4; ++n)
                acc[m][n] = __builtin_amdgcn_mfma_f32_16x16x32_bf16(a[m], b[n], acc[m][n], 0, 0, 0);
    };

    // ---- counted-vmcnt double-buffer pipeline ----
    STAGE(0, 0);
    STAGE(1, 1);      // 8 loads in flight per wave
    #pragma unroll
    for (int t = 0; t < KITERS; ++t) {
        const int cur = t & 1;
        if (t < KITERS - 1) {
            asm volatile("s_waitcnt vmcnt(4)" ::: "memory");  // batch t landed; t+1 in flight
        } else {
            asm volatile("s_waitcnt vmcnt(0)" ::: "memory");
        }
        __builtin_amdgcn_sched_barrier(0);
        __builtin_amdgcn_s_barrier();      // buf cur fully written (all waves)
        COMPUTE(cur);
        __builtin_amdgcn_sched_barrier(0);
        __builtin_amdgcn_s_barrier();      // all waves done reading buf cur
        if (t + 2 < KITERS) STAGE(cur, t + 2);
    }

    // ---- labels (after K-loop so they don't pollute vmcnt counts) ----
    int lj[4];
    #pragma unroll
    for (int n = 0; n < 4; ++n) lj[n] = lab[j0 + wc * 64 + n * 16 + l15];
    int li[16];
    #pragma unroll
    for (int m = 0; m < 4; ++m)
        #pragma unroll
        for (int r = 0; r < 4; ++r)
            li[m * 4 + r] = lab[i0 + wr * 64 + m * 16 + lhi * 4 + r];

    // ---- epilogue ----
    // C[i][j]: i = i0 + wr*64 + m*16 + lhi*4 + r ; j = j0 + wc*64 + n*16 + l15
    #pragma unroll
    for (int m = 0; m < 4; ++m) {
        #pragma unroll
        for (int r = 0; r < 4; ++r) {
            int i   = i0 + wr * 64 + m * 16 + lhi * 4 + r;
            int lir = li[m * 4 + r];
            float pm = 0.0f, nm = BIGF;
            #pragma unroll
            for (int n = 0; n < 4; ++n) {
                float dist = fmaxf(1.0f - acc[m][n][r], 0.0f);
                int j = j0 + wc * 64 + n * 16 + l15;
                if (lir == lj[n]) {
                    if (i != j) pm = fmaxf(pm, dist);
                } else {
                    nm = fminf(nm, dist);
                }
            }
            #pragma unroll
            for (int off = 1; off < 16; off <<= 1) {
                pm = fmaxf(pm, __shfl_xor(pm, off));
                nm = fminf(nm, __shfl_xor(nm, off));
            }
            if (l15 == 0) {
                int loc = wr * 64 + m * 16 + lhi * 4 + r;
                rowp[wc][loc] = pm;
                rown[wc][loc] = nm;
            }
        }
    }

    #pragma unroll
    for (int n = 0; n < 4; ++n) {
        int j   = j0 + wc * 64 + n * 16 + l15;
        int ljn = lj[n];
        float cp = 0.0f, cn = BIGF;
        #pragma unroll
        for (int m = 0; m < 4; ++m) {
            #pragma unroll
            for (int r = 0; r < 4; ++r) {
                float dist = fmaxf(1.0f - acc[m][n][r], 0.0f);
                int i = i0 + wr * 64 + m * 16 + lhi * 4 + r;
                if (li[m * 4 + r] == ljn) {
                    if (i != j) cp = fmaxf(cp, dist);
                } else {
                    cn = fminf(cn, dist);
                }
            }
        }
        #pragma unroll
        for (int off = 16; off < 64; off <<= 1) {
            cp = fmaxf(cp, __shfl_xor(cp, off));
            cn = fminf(cn, __shfl_xor(cn, off));
        }
        if (lhi == 0) {
            int loc = wc * 64 + n * 16 + l15;
            colp[wr][loc] = cp;
            coln[wr][loc] = cn;
        }
    }

    __syncthreads();

    if (tid < BM) {
        float pmv = fmaxf(rowp[0][tid], rowp[1][tid]);
        float nmv = fminf(rown[0][tid], rown[1][tid]);
        atomicMax(hp + i0 + tid, __float_as_uint(pmv));
        atomicMin(hn + i0 + tid, __float_as_uint(nmv));
    } else {
        int c = tid - BM;
        float pmv = fmaxf(colp[0][c], colp[1][c]);
        float nmv = fminf(coln[0][c], coln[1][c]);
        atomicMax(hp + j0 + c, __float_as_uint(pmv));
        atomicMin(hn + j0 + c, __float_as_uint(nmv));
    }
}

// ---------------- kernel 3: finalize ----------------
__global__ __launch_bounds__(1024) void final_k(const int* __restrict__ lab,
                                                const unsigned* __restrict__ hp,
                                                const unsigned* __restrict__ hn,
                                                float* __restrict__ out) {
    __shared__ int   cnt[NLBL];
    __shared__ float ssum[16];
    __shared__ int   scnt[16];
    int t = threadIdx.x;
    for (int i = t; i < NLBL; i += 1024) cnt[i] = 0;
    __syncthreads();
    for (int i = t; i < BATCH; i += 1024) atomicAdd(&cnt[lab[i]], 1);
    __syncthreads();

    float lsum = 0.0f;
    int   lcnt = 0;
    for (int i = t; i < BATCH; i += 1024) {
        int c = cnt[lab[i]];
        if ((c > 1) && (c < BATCH)) {
            float per = fmaxf(__uint_as_float(hp[i]) - __uint_as_float(hn[i]) + MARGIN, 0.0f);
            lsum += per;
            lcnt += 1;
        }
    }
    #pragma unroll
    for (int off = 1; off < 64; off <<= 1) {
        lsum += __shfl_xor(lsum, off);
        lcnt += __shfl_xor(lcnt, off);
    }
    int w = t >> 6;
    if ((t & 63) == 0) { ssum[w] = lsum; scnt[w] = lcnt; }
    __syncthreads();
    if (t == 0) {
        float s = 0.0f; int c2 = 0;
        #pragma unroll
        for (int i = 0; i < 16; ++i) { s += ssum[i]; c2 += scnt[i]; }
        out[0] = s / (float)max(c2, 1);
    }
}

// ---------------- launcher ----------------
extern "C" void kernel_launch(void* const* d_in, const int* in_sizes, int n_in,
                              void* d_out, int out_size, void* d_ws, size_t ws_size,
                              hipStream_t stream) {
    const float* emb = (const float*)d_in[0];
    const int*   lab = (const int*)d_in[1];

    char* base = (char*)d_ws;
    unsigned short* Hi = (unsigned short*)base;                       // 4 MB
    unsigned* hp = (unsigned*)(base + (size_t)BATCH * DIM * 2);       // 16 KB
    unsigned* hn = hp + BATCH;                                        // 16 KB

    normalize_k<<<BATCH / 4, 256, 0, stream>>>(emb, Hi, hp, hn);
    mine_k<<<NPAIR, 256, 0, stream>>>(Hi, lab, hp, hn);
    final_k<<<1, 1024, 0, stream>>>(lab, hp, hn, (float*)d_out);
}

// Round 11
// 35.496 us; speedup vs baseline: 1.3434x; 1.0481x over previous
//
#include <hip/hip_runtime.h>
#include <hip/hip_bf16.h>

#define BATCH 4096
#define DIM   512
#define NLBL  512
#define BIGF  1e4f
#define MARGIN 1.0f

#define BM 128        // tile (rows = cols)
#define BK 32         // bf16 elems per K-step
#define NT (BATCH/BM) // 32
#define NPAIR (NT*(NT+1)/2)  // 528
#define KITERS (DIM/BK)      // 16

// Tiled layout: HiT[tileR][chunk][128][32] bf16. One (tileR,chunk) panel =
// 128*32*2B = 8KB CONTIGUOUS. elem(r,k) = (r>>7)*65536 + (k>>5)*4096 + (r&127)*32 + (k&31)
#define PANEL_E 4096          // elems per panel
#define TILE_E  65536         // elems per row-tile (16 panels)

using f32x4  = __attribute__((ext_vector_type(4))) float;
using bf16x8 = __attribute__((ext_vector_type(8))) short;

// ---- compile-time pair table: supercell-compact enumeration of the triangle ----
struct PairTab { unsigned char bi[NPAIR]; unsigned char bj[NPAIR]; };
constexpr PairTab make_tab() {
    PairTab t{};
    int idx = 0;
    for (int BI = 0; BI < 8; ++BI)
        for (int BJ = BI; BJ < 8; ++BJ)
            for (int ii = 0; ii < 4; ++ii)
                for (int jj = 0; jj < 4; ++jj) {
                    int i = BI * 4 + ii, j = BJ * 4 + jj;
                    if (i <= j) {
                        t.bi[idx] = (unsigned char)i;
                        t.bj[idx] = (unsigned char)j;
                        ++idx;
                    }
                }
    return t;
}
__device__ constexpr PairTab PT = make_tab();

__device__ __forceinline__ unsigned short f2bf(float x) {
    __hip_bfloat16 h = __float2bfloat16(x);
    return *reinterpret_cast<unsigned short*>(&h);
}

#define GLOAD16(gp, lp) \
    __builtin_amdgcn_global_load_lds((const __attribute__((address_space(1))) void*)(gp), \
                                     (__attribute__((address_space(3))) void*)(lp), 16, 0, 0)

// ---------------- kernel 1: row L2-normalize -> bf16 TILED layout (+ hp/hn init) ----------------
__global__ __launch_bounds__(256) void normalize_k(const float* __restrict__ emb,
                                                   unsigned short* __restrict__ HiT,
                                                   unsigned* __restrict__ hp,
                                                   unsigned* __restrict__ hn) {
    int wave = threadIdx.x >> 6;
    int lane = threadIdx.x & 63;
    int row  = blockIdx.x * 4 + wave;
    const float4* src = (const float4*)(emb + (size_t)row * DIM);
    float4 v0 = src[lane * 2];
    float4 v1 = src[lane * 2 + 1];
    float ss = v0.x*v0.x + v0.y*v0.y + v0.z*v0.z + v0.w*v0.w
             + v1.x*v1.x + v1.y*v1.y + v1.z*v1.z + v1.w*v1.w;
    #pragma unroll
    for (int off = 1; off < 64; off <<= 1) ss += __shfl_xor(ss, off);
    float scale = 1.0f / fmaxf(sqrtf(ss), 1e-12f);
    bf16x8 o;
    o[0] = (short)f2bf(v0.x * scale);
    o[1] = (short)f2bf(v0.y * scale);
    o[2] = (short)f2bf(v0.z * scale);
    o[3] = (short)f2bf(v0.w * scale);
    o[4] = (short)f2bf(v1.x * scale);
    o[5] = (short)f2bf(v1.y * scale);
    o[6] = (short)f2bf(v1.z * scale);
    o[7] = (short)f2bf(v1.w * scale);
    // lane l holds k = l*8 .. l*8+7  ->  chunk l>>2, within-chunk col (l&3)*8
    size_t off = (size_t)(row >> 7) * TILE_E + (size_t)(lane >> 2) * PANEL_E
               + (size_t)(row & 127) * 32 + (lane & 3) * 8;
    *(bf16x8*)(HiT + off) = o;
    if (lane == 0) {
        hp[row] = 0u;
        hn[row] = __float_as_uint(BIGF);
    }
}

// ---------------- kernel 2: fused bf16 MFMA sim + batch-hard mining ----------------
// R7 pipeline (BK=32 dbuf, counted vmcnt, 4 blocks/CU) with CONTIGUOUS panel
// staging: each GLOAD16 reads 1KB sequential (8 full 128B lines) instead of 16
// scattered 64B segments -> half the L1/L2 transactions, half the L2 bytes.
// Swizzle folded into src permutation (16B chunks within 64B rows only).
__global__ __launch_bounds__(256, 4) void mine_k(const unsigned short* __restrict__ HiT,
                                                 const int* __restrict__ lab,
                                                 unsigned* __restrict__ hp,
                                                 unsigned* __restrict__ hn) {
    __shared__ __attribute__((aligned(16))) unsigned short As[2][BM * BK]; // 16 KB
    __shared__ __attribute__((aligned(16))) unsigned short Bs[2][BM * BK]; // 16 KB
    __shared__ float rowp[2][BM], rown[2][BM], colp[2][BM], coln[2][BM];   // 4 KB

    int orig = (int)blockIdx.x;
    int p = (orig & 7) * (NPAIR / 8) + (orig >> 3);
    const int bi = PT.bi[p];
    const int bj = PT.bj[p];
    const int i0 = bi * BM;
    const int j0 = bj * BM;

    const int tid  = threadIdx.x;
    const int w    = tid >> 6;
    const int lane = tid & 63;
    const int wr   = w >> 1;
    const int wc   = w & 1;
    const int l15  = lane & 15;
    const int lhi  = lane >> 4;     // 0..3 : 16B k-chunk within 64B row

    f32x4 acc[4][4] = {};
    const char* HiB = (const char*)HiT;

    // stage: wave w covers panel rows w*32..w*32+31; q segment = 16 rows = 1KB.
    // lane l -> LDS slot (R = w*32+q*16+(l>>2), chunk c=l&3); src chunk = c^((R>>1)&3)
    // (permutes within each 64B row -> still one contiguous 1KB transaction set).
    auto STAGE = [&](int buf, int t) {
        const size_t pa = ((size_t)bi * 16 + t) * (PANEL_E * 2);  // panel byte base (A)
        const size_t pb = ((size_t)bj * 16 + t) * (PANEL_E * 2);  // panel byte base (B)
        const int rrel = lane >> 2;               // 0..15
        #pragma unroll
        for (int q = 0; q < 2; ++q) {
            const int R   = w * 32 + q * 16 + rrel;
            const int sc  = (lane & 3) ^ ((R >> 1) & 3);
            const int soff = (w * 2048 + q * 1024) + rrel * 64 + (sc << 4);
            GLOAD16(HiB + pa + soff, (char*)As[buf] + (w * 32 + q * 16) * 64);
            GLOAD16(HiB + pb + soff, (char*)Bs[buf] + (w * 32 + q * 16) * 64);
        }
    };
    // compute: identical to R7 (0 measured bank conflicts).
    auto COMPUTE = [&](int buf) {
        bf16x8 a[4], b[4];
        #pragma unroll
        for (int m = 0; m < 4; ++m) {
            int row = wr * 64 + m * 16 + l15;
            int cp  = lhi ^ ((row >> 1) & 3);
            a[m] = *(const bf16x8*)((const char*)As[buf] + row * 64 + (cp << 4));
        }
        #pragma unroll
        for (int n = 0; n < 4; ++n) {
            int row = wc * 64 + n * 16 + l15;
            int cp  = lhi ^ ((row >> 1) & 3);
            b[n] = *(const bf16x8*)((const char*)Bs[buf] + row * 64 + (cp << 4));
        }
        #pragma unroll
        for (int m = 0; m < 4; ++m)
            #pragma unroll
            for (int n = 0; n < 4; ++n)
                acc[m][n] = __builtin_amdgcn_mfma_f32_16x16x32_bf16(a[m], b[n], acc[m][n], 0, 0, 0);
    };

    // ---- counted-vmcnt double-buffer pipeline ----
    STAGE(0, 0);
    STAGE(1, 1);      // 8 loads in flight per wave
    #pragma unroll
    for (int t = 0; t < KITERS; ++t) {
        const int cur = t & 1;
        if (t < KITERS - 1) {
            asm volatile("s_waitcnt vmcnt(4)" ::: "memory");  // batch t landed; t+1 in flight
        } else {
            asm volatile("s_waitcnt vmcnt(0)" ::: "memory");
        }
        __builtin_amdgcn_sched_barrier(0);
        __builtin_amdgcn_s_barrier();      // buf cur fully written (all waves)
        COMPUTE(cur);
        __builtin_amdgcn_sched_barrier(0);
        __builtin_amdgcn_s_barrier();      // all waves done reading buf cur
        if (t + 2 < KITERS) STAGE(cur, t + 2);
    }

    // ---- labels ----
    int lj[4];
    #pragma unroll
    for (int n = 0; n < 4; ++n) lj[n] = lab[j0 + wc * 64 + n * 16 + l15];
    int li[16];
    #pragma unroll
    for (int m = 0; m < 4; ++m)
        #pragma unroll
        for (int r = 0; r < 4; ++r)
            li[m * 4 + r] = lab[i0 + wr * 64 + m * 16 + lhi * 4 + r];

    // ---- epilogue ----
    // C[i][j]: i = i0 + wr*64 + m*16 + lhi*4 + r ; j = j0 + wc*64 + n*16 + l15
    #pragma unroll
    for (int m = 0; m < 4; ++m) {
        #pragma unroll
        for (int r = 0; r < 4; ++r) {
            int i   = i0 + wr * 64 + m * 16 + lhi * 4 + r;
            int lir = li[m * 4 + r];
            float pm = 0.0f, nm = BIGF;
            #pragma unroll
            for (int n = 0; n < 4; ++n) {
                float dist = fmaxf(1.0f - acc[m][n][r], 0.0f);
                int j = j0 + wc * 64 + n * 16 + l15;
                if (lir == lj[n]) {
                    if (i != j) pm = fmaxf(pm, dist);
                } else {
                    nm = fminf(nm, dist);
                }
            }
            #pragma unroll
            for (int off = 1; off < 16; off <<= 1) {
                pm = fmaxf(pm, __shfl_xor(pm, off));
                nm = fminf(nm, __shfl_xor(nm, off));
            }
            if (l15 == 0) {
                int loc = wr * 64 + m * 16 + lhi * 4 + r;
                rowp[wc][loc] = pm;
                rown[wc][loc] = nm;
            }
        }
    }

    #pragma unroll
    for (int n = 0; n < 4; ++n) {
        int j   = j0 + wc * 64 + n * 16 + l15;
        int ljn = lj[n];
        float cp = 0.0f, cn = BIGF;
        #pragma unroll
        for (int m = 0; m < 4; ++m) {
            #pragma unroll
            for (int r = 0; r < 4; ++r) {
                float dist = fmaxf(1.0f - acc[m][n][r], 0.0f);
                int i = i0 + wr * 64 + m * 16 + lhi * 4 + r;
                if (li[m * 4 + r] == ljn) {
                    if (i != j) cp = fmaxf(cp, dist);
                } else {
                    cn = fminf(cn, dist);
                }
            }
        }
        #pragma unroll
        for (int off = 16; off < 64; off <<= 1) {
            cp = fmaxf(cp, __shfl_xor(cp, off));
            cn = fminf(cn, __shfl_xor(cn, off));
        }
        if (lhi == 0) {
            int loc = wc * 64 + n * 16 + l15;
            colp[wr][loc] = cp;
            coln[wr][loc] = cn;
        }
    }

    __syncthreads();

    if (tid < BM) {
        float pmv = fmaxf(rowp[0][tid], rowp[1][tid]);
        float nmv = fminf(rown[0][tid], rown[1][tid]);
        atomicMax(hp + i0 + tid, __float_as_uint(pmv));
        atomicMin(hn + i0 + tid, __float_as_uint(nmv));
    } else {
        int c = tid - BM;
        float pmv = fmaxf(colp[0][c], colp[1][c]);
        float nmv = fminf(coln[0][c], coln[1][c]);
        atomicMax(hp + j0 + c, __float_as_uint(pmv));
        atomicMin(hn + j0 + c, __float_as_uint(nmv));
    }
}

// ---------------- kernel 3: finalize ----------------
__global__ __launch_bounds__(1024) void final_k(const int* __restrict__ lab,
                                                const unsigned* __restrict__ hp,
                                                const unsigned* __restrict__ hn,
                                                float* __restrict__ out) {
    __shared__ int   cnt[NLBL];
    __shared__ float ssum[16];
    __shared__ int   scnt[16];
    int t = threadIdx.x;
    for (int i = t; i < NLBL; i += 1024) cnt[i] = 0;
    __syncthreads();
    for (int i = t; i < BATCH; i += 1024) atomicAdd(&cnt[lab[i]], 1);
    __syncthreads();

    float lsum = 0.0f;
    int   lcnt = 0;
    for (int i = t; i < BATCH; i += 1024) {
        int c = cnt[lab[i]];
        if ((c > 1) && (c < BATCH)) {
            float per = fmaxf(__uint_as_float(hp[i]) - __uint_as_float(hn[i]) + MARGIN, 0.0f);
            lsum += per;
            lcnt += 1;
        }
    }
    #pragma unroll
    for (int off = 1; off < 64; off <<= 1) {
        lsum += __shfl_xor(lsum, off);
        lcnt += __shfl_xor(lcnt, off);
    }
    int w = t >> 6;
    if ((t & 63) == 0) { ssum[w] = lsum; scnt[w] = lcnt; }
    __syncthreads();
    if (t == 0) {
        float s = 0.0f; int c2 = 0;
        #pragma unroll
        for (int i = 0; i < 16; ++i) { s += ssum[i]; c2 += scnt[i]; }
        out[0] = s / (float)max(c2, 1);
    }
}

// ---------------- launcher ----------------
extern "C" void kernel_launch(void* const* d_in, const int* in_sizes, int n_in,
                              void* d_out, int out_size, void* d_ws, size_t ws_size,
                              hipStream_t stream) {
    const float* emb = (const float*)d_in[0];
    const int*   lab = (const int*)d_in[1];

    char* base = (char*)d_ws;
    unsigned short* HiT = (unsigned short*)base;                      // 4 MB tiled
    unsigned* hp = (unsigned*)(base + (size_t)BATCH * DIM * 2);       // 16 KB
    unsigned* hn = hp + BATCH;                                        // 16 KB

    normalize_k<<<BATCH / 4, 256, 0, stream>>>(emb, HiT, hp, hn);
    mine_k<<<NPAIR, 256, 0, stream>>>(HiT, lab, hp, hn);
    final_k<<<1, 1024, 0, stream>>>(lab, hp, hn, (float*)d_out);
}